// Round 6
// baseline (10372.385 us; speedup 1.0000x reference)
//
#include <hip/hip_runtime.h>

// ---------------- problem constants ----------------
#define T_SEQ 512
#define P_PRED 32
#define TP 544            // T_SEQ + P_PRED
#define BATCH 256
#define H 512
#define G4H 2048
// ---------------- kernel config --------------------
#define GRID 128          // 64 col-groups x 2 batch-groups
#define BLOCK 256         // 4 waves
#define NH 8              // h-columns per WG (x4 gates = 32 gate-cols)
#define ROWS 128          // batch rows per WG
#define HB (BATCH*H*2)    // bytes per h double-buffer slot

typedef _Float16 half8 __attribute__((ext_vector_type(8)));
typedef float floatx4 __attribute__((ext_vector_type(4)));
typedef __amdgpu_buffer_rsrc_t rsrc_t;

// gfx950 CPol: bit0=SC0, bit4=SC1. Stores: write-through to LIC (coherence pt).
// Loads: normal cached (L1+L2); freshness via buffer_inv in the barrier.
#define SC01 17

#define MFMA(a,b,c) __builtin_amdgcn_mfma_f32_16x16x32_f16((a),(b),(c),0,0,0)

// ---------------- device-global state --------------
__device__ __attribute__((aligned(16))) _Float16 g_h1[2][BATCH*H];
__device__ __attribute__((aligned(16))) _Float16 g_h2[2][BATCH*H];
__device__ __attribute__((aligned(16))) float g_opart[TP*BATCH*64]; // o partials [t][row][cg]
__device__ __attribute__((aligned(16))) float g_seqT[T_SEQ*BATCH];
__device__ unsigned g_cnt;

__device__ __forceinline__ rsrc_t mkrsrc(void* p){
  return __builtin_amdgcn_make_buffer_rsrc(p, (short)0, -1, 0x00020000);
}
__device__ __forceinline__ half8 ld_h8(rsrc_t r, int off){
  auto v = __builtin_amdgcn_raw_buffer_load_b128(r, off, 0, 0);   // cached
  return __builtin_bit_cast(half8, v);
}
__device__ __forceinline__ floatx4 ld_f4(rsrc_t r, int off){
  auto v = __builtin_amdgcn_raw_buffer_load_b128(r, off, 0, 0);   // cached
  return __builtin_bit_cast(floatx4, v);
}
__device__ __forceinline__ void st_f(rsrc_t r, int off, float v){
  __builtin_amdgcn_raw_buffer_store_b32(__builtin_bit_cast(unsigned, v), r, off, 0, SC01);
}

__device__ __forceinline__ float sigm(float x){ return 1.0f/(1.0f + __expf(-x)); }
__device__ __forceinline__ float tanh_f(float x){ return 1.0f - 2.0f/(1.0f + __expf(2.0f*x)); }

// Grid barrier. Release = vmcnt drain of sc write-through stores (already at
// LIC when acked). Acquire = agent fence -> buffer_inv (L1+L2 tag invalidate,
// nothing dirty so no writeback, refills come from LIC not HBM).
__device__ __forceinline__ void gbar(unsigned target){
  __builtin_amdgcn_s_waitcnt(0);
  __syncthreads();
  if (threadIdx.x == 0){
    __hip_atomic_fetch_add(&g_cnt, 1u, __ATOMIC_RELAXED, __HIP_MEMORY_SCOPE_AGENT);
    while (__hip_atomic_load(&g_cnt, __ATOMIC_RELAXED, __HIP_MEMORY_SCOPE_AGENT) < target)
      __builtin_amdgcn_s_sleep(4);
    __builtin_amdgcn_fence(__ATOMIC_ACQUIRE, "agent");
  }
  __syncthreads();
}

// One pipeline phase. DOL1: h1 = lstm(x, h1prev), Wh1 in regs. XSEL: 0 = x from
// seqT, 1 = x from o-partial reduce (+bl). DOL2: h2 = lstm(h1r, h2prev) with
// Wx2/Wh2 in LDS + o-partial store; z2's x-term reuses the h1r A-fragments.
template<bool DOL1, bool DOL2, int XSEL>
__device__ __forceinline__ void do_phase(
    rsrc_t rh1, rsrc_t rh2, rsrc_t rop, rsrc_t rsq,
    int o_h1r, int o_h2r, int o_h1w, int o_h2w,
    int o_x, float xadd, int t_out,
    const half8 (&wh1f)[16][2], const _Float16* __restrict__ ldsw,
    float b1a, float b1b, float b2a, float b2b,
    float wxa, float wxb, float wlv,
    float (&c1v)[2][4], float (&c2v)[2][4],
    int rowbase, int ln, int quad, int n0)
{
  floatx4 z1[2][2], z2[2][2];
  floatx4 zf4 = {0.f,0.f,0.f,0.f};
  z1[0][0]=zf4; z1[0][1]=zf4; z1[1][0]=zf4; z1[1][1]=zf4;
  z2[0][0]=zf4; z2[0][1]=zf4; z2[1][0]=zf4; z2[1][1]=zf4;

  float xv[2][4];
  if (DOL1){
    #pragma unroll
    for (int mt=0; mt<2; ++mt){
      if (XSEL == 0){
        floatx4 x4 = ld_f4(rsq, o_x + (rowbase + mt*16 + quad*4)*4);
        #pragma unroll
        for (int r=0; r<4; ++r) xv[mt][r] = x4[r] + xadd;
      } else {
        #pragma unroll
        for (int r=0; r<4; ++r){
          const int row = rowbase + mt*16 + quad*4 + r;
          floatx4 p4 = ld_f4(rop, o_x + (row*64 + ln*4)*4);
          float s = p4[0] + p4[1] + p4[2] + p4[3];
          s += __shfl_xor(s, 1, 64);
          s += __shfl_xor(s, 2, 64);
          s += __shfl_xor(s, 4, 64);
          s += __shfl_xor(s, 8, 64);
          xv[mt][r] = s + xadd;
        }
      }
    }
  }

  const int a_r0 = (rowbase + ln)*H*2;
  const int a_r1 = (rowbase + 16 + ln)*H*2;
  const int l7 = ln & 7;

  #pragma unroll
  for (int kk = 0; kk < 16; ++kk){
    const int k0b = (kk*32 + quad*8)*2;
    half8 a10 = ld_h8(rh1, o_h1r + a_r0 + k0b);
    half8 a11 = ld_h8(rh1, o_h1r + a_r1 + k0b);
    if (DOL1){
      z1[0][0] = MFMA(a10, wh1f[kk][0], z1[0][0]);
      z1[1][0] = MFMA(a11, wh1f[kk][0], z1[1][0]);
      z1[0][1] = MFMA(a10, wh1f[kk][1], z1[0][1]);
      z1[1][1] = MFMA(a11, wh1f[kk][1], z1[1][1]);
    }
    if (DOL2){
      const int sw = (((kk*4 + quad) ^ l7) << 3);   // XOR-swizzled k-granule
      half8 c0 = *(const half8*)(ldsw + (ln)*512      + sw);   // Wx2 tile0
      half8 c1 = *(const half8*)(ldsw + (16+ln)*512   + sw);   // Wx2 tile1
      z2[0][0] = MFMA(a10, c0, z2[0][0]);
      z2[1][0] = MFMA(a11, c0, z2[1][0]);
      z2[0][1] = MFMA(a10, c1, z2[0][1]);
      z2[1][1] = MFMA(a11, c1, z2[1][1]);
      half8 a20 = ld_h8(rh2, o_h2r + a_r0 + k0b);
      half8 a21 = ld_h8(rh2, o_h2r + a_r1 + k0b);
      half8 d0 = *(const half8*)(ldsw + (32+ln)*512   + sw);   // Wh2 tile0
      half8 d1 = *(const half8*)(ldsw + (48+ln)*512   + sw);   // Wh2 tile1
      z2[0][0] = MFMA(a20, d0, z2[0][0]);
      z2[1][0] = MFMA(a21, d0, z2[1][0]);
      z2[0][1] = MFMA(a20, d1, z2[0][1]);
      z2[1][1] = MFMA(a21, d1, z2[1][1]);
    }
  }

  const bool lo = (ln < 8);
  const bool evn = ((ln & 1) == 0);
  if (DOL1){
    #pragma unroll
    for (int mt=0; mt<2; ++mt){
      #pragma unroll
      for (int r=0; r<4; ++r){
        const int row = rowbase + mt*16 + quad*4 + r;
        float za = z1[mt][0][r] + xv[mt][r]*wxa + b1a;   // gates i/f (cols 0-15)
        float zb = z1[mt][1][r] + xv[mt][r]*wxb + b1b;   // gates o/g (cols 16-31)
        float pa = __shfl_xor(za, 8, 64);
        float pb = __shfl_xor(zb, 8, 64);
        float zi = lo ? za : pa, zf = lo ? pa : za;
        float zo = lo ? zb : pb, zg = lo ? pb : zb;
        float ig = sigm(zi), fg = sigm(zf), og = sigm(zo), gg = tanh_f(zg);
        float c = fg*c1v[mt][r] + ig*gg;
        c1v[mt][r] = c;
        float h = og*tanh_f(c);
        unsigned hu = (unsigned)(unsigned short)__builtin_bit_cast(unsigned short, (_Float16)h);
        unsigned pn = (unsigned)__shfl_xor((int)hu, 1, 64);
        if (lo && evn)
          st_f(rh1, o_h1w + row*H*2 + (n0+ln)*2,
               __builtin_bit_cast(float, hu | (pn<<16)));
      }
    }
  }
  if (DOL2){
    #pragma unroll
    for (int mt=0; mt<2; ++mt){
      #pragma unroll
      for (int r=0; r<4; ++r){
        const int row = rowbase + mt*16 + quad*4 + r;
        float za = z2[mt][0][r] + b2a;
        float zb = z2[mt][1][r] + b2b;
        float pa = __shfl_xor(za, 8, 64);
        float pb = __shfl_xor(zb, 8, 64);
        float zi = lo ? za : pa, zf = lo ? pa : za;
        float zo = lo ? zb : pb, zg = lo ? pb : zb;
        float ig = sigm(zi), fg = sigm(zf), og = sigm(zo), gg = tanh_f(zg);
        float c = fg*c2v[mt][r] + ig*gg;
        c2v[mt][r] = c;
        float h = og*tanh_f(c);
        unsigned hu = (unsigned)(unsigned short)__builtin_bit_cast(unsigned short, (_Float16)h);
        unsigned pn = (unsigned)__shfl_xor((int)hu, 1, 64);
        if (lo && evn)
          st_f(rh2, o_h2w + row*H*2 + (n0+ln)*2,
               __builtin_bit_cast(float, hu | (pn<<16)));
        float po = lo ? h*wlv : 0.f;
        po += __shfl_xor(po, 1, 64);
        po += __shfl_xor(po, 2, 64);
        po += __shfl_xor(po, 4, 64);
        if (ln == 0)
          st_f(rop, (t_out*(BATCH*64) + row*64 + (n0>>3))*4, po);
      }
    }
  }
}

__global__ void reset_cnt_kernel(){ g_cnt = 0u; }

__global__ __launch_bounds__(BLOCK, 1) void sinernn_kernel(
    const float* __restrict__ seq, const float* __restrict__ Wx1,
    const float* __restrict__ bx1, const float* __restrict__ Wh1,
    const float* __restrict__ bh1, const float* __restrict__ Wx2,
    const float* __restrict__ bx2, const float* __restrict__ Wh2,
    const float* __restrict__ bh2, const float* __restrict__ Wl,
    const float* __restrict__ bl,  float* __restrict__ out)
{
  // LDS: Wx2 (rows 0-31) and Wh2 (rows 32-63), fp16, XOR-swizzled k-granules.
  __shared__ _Float16 ldsw[2*32*512];

  const int tid  = threadIdx.x;
  const int wg   = blockIdx.x;
  const int cg   = wg >> 1;            // column group 0..63
  const int bg   = wg & 1;             // batch group 0..1 (== XCD parity: per-XCD bg homogeneous)
  const int n0   = cg * NH;
  const int wave = tid >> 6;
  const int lane = tid & 63;
  const int ln   = lane & 15;
  const int quad = lane >> 4;
  const int rowbase = bg*ROWS + wave*32;

  rsrc_t rh1 = mkrsrc((void*)&g_h1[0][0]);
  rsrc_t rh2 = mkrsrc((void*)&g_h2[0][0]);
  rsrc_t rop = mkrsrc((void*)&g_opart[0]);
  rsrc_t rsq = mkrsrc((void*)&g_seqT[0]);

  // ---- prologue: zero h(-1) buffers, transpose seq (all via sc-stores) ----
  {
    const int gt = wg*BLOCK + tid;
    for (int i = gt; i < BATCH*H/2; i += GRID*BLOCK){
      st_f(rh1, HB + i*4, 0.f);
      st_f(rh2, HB + i*4, 0.f);
    }
    for (int i = gt; i < T_SEQ*BATCH; i += GRID*BLOCK){
      int t = i >> 8, b = i & (BATCH-1);
      st_f(rsq, i*4, seq[b*T_SEQ + t]);
    }
  }
  // ---- stage Wx2/Wh2 into LDS (fp16, swizzled) ----
  for (int idx = tid; idx < 2*32*64; idx += BLOCK){
    int m   = idx >> 11;            // 0: Wx2, 1: Wh2
    int rem = idx & 2047;
    int cl  = rem >> 6;             // gate-col 0..31
    int g   = rem & 63;             // k-granule
    int row = m*32 + cl;
    int gc  = (cl>>3)*H + n0 + (cl&7);
    const float* W = m ? Wh2 : Wx2;
    int pbase = row*512 + ((g ^ (row&7)) << 3);
    #pragma unroll
    for (int j = 0; j < 8; ++j)
      ldsw[pbase + j] = (_Float16)W[(g*8+j)*G4H + gc];
  }
  // ---- per-lane constants ----
  const int gcA = (ln>>3)*H + n0 + (ln&7);          // col tile0 (gates i/f)
  const int gcB = (2 + (ln>>3))*H + n0 + (ln&7);    // col tile1 (gates o/g)
  const float b1a = bx1[gcA] + bh1[gcA], b1b = bx1[gcB] + bh1[gcB];
  const float b2a = bx2[gcA] + bh2[gcA], b2b = bx2[gcB] + bh2[gcB];
  const float wxa = Wx1[gcA], wxb = Wx1[gcB];
  const float wlv = (ln < 8) ? Wl[n0 + ln] : 0.f;
  const float blv = bl[0];

  // ---- stage Wh1 B-fragments into registers (128 VGPRs) ----
  half8 wh1f[16][2];
  #pragma unroll
  for (int kk = 0; kk < 16; ++kk){
    #pragma unroll
    for (int j = 0; j < 8; ++j){
      const int k = kk*32 + quad*8 + j;
      wh1f[kk][0][j] = (_Float16)Wh1[k*G4H + gcA];
      wh1f[kk][1][j] = (_Float16)Wh1[k*G4H + gcB];
    }
  }

  float c1v[2][4] = {{0.f,0.f,0.f,0.f},{0.f,0.f,0.f,0.f}};
  float c2v[2][4] = {{0.f,0.f,0.f,0.f},{0.f,0.f,0.f,0.f}};

  unsigned bidx = 0;
  __syncthreads();                   // LDS staging done
  gbar((++bidx) * (unsigned)GRID);   // prologue visible grid-wide

  // ---- main pipelined region: phase p computes h1(p) and h2(p-1) ----
  for (int p = 0; p < T_SEQ; ++p){
    const int b_h1r = ((p+1)&1)*HB;
    const int b_h1w = (p&1)*HB;
    if (p == 0)
      do_phase<true,false,0>(rh1,rh2,rop,rsq, b_h1r,0, b_h1w,0,
                             0, 0.f, -1,
                             wh1f, ldsw, b1a,b1b,b2a,b2b,wxa,wxb,wlv,
                             c1v, c2v, rowbase, ln, quad, n0);
    else
      do_phase<true,true,0>(rh1,rh2,rop,rsq, b_h1r,(p&1)*HB, b_h1w,((p+1)&1)*HB,
                            p*BATCH*4, 0.f, p-1,
                            wh1f, ldsw, b1a,b1b,b2a,b2b,wxa,wxb,wlv,
                            c1v, c2v, rowbase, ln, quad, n0);
    gbar((++bidx) * (unsigned)GRID);
  }

  // ---- drain + autoregressive predict ----
  for (int s = T_SEQ-1; s < TP; ++s){
    do_phase<false,true,0>(rh1,rh2,rop,rsq, (s&1)*HB,((s+1)&1)*HB, 0,(s&1)*HB,
                           0, 0.f, s,
                           wh1f, ldsw, b1a,b1b,b2a,b2b,wxa,wxb,wlv,
                           c1v, c2v, rowbase, ln, quad, n0);
    gbar((++bidx) * (unsigned)GRID);
    if (s + 1 < TP){
      do_phase<true,false,1>(rh1,rh2,rop,rsq, (s&1)*HB,0, ((s+1)&1)*HB,0,
                             s*(BATCH*64)*4, blv, -1,
                             wh1f, ldsw, b1a,b1b,b2a,b2b,wxa,wxb,wlv,
                             c1v, c2v, rowbase, ln, quad, n0);
      gbar((++bidx) * (unsigned)GRID);
    }
  }

  // ---- epilogue: out[b][t] = sum_cg opart[t][b][cg] + bl ----
  {
    const int b0 = wg*2 + (tid >> 7);
    const int tl = tid & 127;
    for (int t = tl; t < TP; t += 128){
      const int base = (t*BATCH + b0)*64*4;
      float s = 0.f;
      #pragma unroll
      for (int i = 0; i < 16; ++i){
        floatx4 v = ld_f4(rop, base + i*16);
        s += v[0] + v[1] + v[2] + v[3];
      }
      out[b0*TP + t] = s + blv;
    }
  }
}

extern "C" void kernel_launch(void* const* d_in, const int* in_sizes, int n_in,
                              void* d_out, int out_size, void* d_ws, size_t ws_size,
                              hipStream_t stream) {
  const float* seq = (const float*)d_in[0];
  // d_in[1] = predict (=32, hardcoded)
  const float* Wx1 = (const float*)d_in[2];
  const float* bx1 = (const float*)d_in[3];
  const float* Wh1 = (const float*)d_in[4];
  const float* bh1 = (const float*)d_in[5];
  const float* Wx2 = (const float*)d_in[6];
  const float* bx2 = (const float*)d_in[7];
  const float* Wh2 = (const float*)d_in[8];
  const float* bh2 = (const float*)d_in[9];
  const float* Wl  = (const float*)d_in[10];
  const float* bl  = (const float*)d_in[11];
  float* out = (float*)d_out;

  // Stream-ordered reset of the barrier counter (graph-capture safe).
  reset_cnt_kernel<<<1, 1, 0, stream>>>();

  sinernn_kernel<<<dim3(GRID), dim3(BLOCK), 0, stream>>>(
      seq, Wx1, bx1, Wh1, bh1, Wx2, bx2, Wh2, bh2, Wl, bl, out);
}

// Round 8
// 7487.825 us; speedup vs baseline: 1.3852x; 1.3852x over previous
//
#include <hip/hip_runtime.h>

// ---------------- problem constants ----------------
#define T_SEQ 512
#define P_PRED 32
#define TP 544            // T_SEQ + P_PRED
#define BATCH 256
#define H 512
#define G4H 2048
// ---------------- kernel config --------------------
// 256 WGs = 8 row-groups x 32 col-slots. group = blockIdx&7 (XCD-colocated
// under round-robin dispatch: perf bonus only). Group g owns batch rows
// [32g,32g+32). Slot s owns h-cols [16s,16s+16); wave w owns h-cols
// 16s+4w..+4 (16 gate-cols). Weights in VGPRs (192/lane). All cross-WG data
// via sc0|sc1 at LIC (placement-safe); barriers = device-scope atomics on 8
// private lines. 1 block/CU -> all 256 blocks co-resident (no deadlock).
#define GRID 256
#define BLOCK 256
#define HBUF (BATCH*H)      // elements per h double-buffer slot
#define HBYTES (HBUF*2)
#define SC01 17             // CPol: SC0|SC1 -> bypass L1+L2, operate at LIC

typedef _Float16 half8 __attribute__((ext_vector_type(8)));
typedef float floatx4 __attribute__((ext_vector_type(4)));
typedef __amdgpu_buffer_rsrc_t rsrc_t;

#define MFMA(a,b,c) __builtin_amdgcn_mfma_f32_16x16x32_f16((a),(b),(c),0,0,0)

// ---------------- device-global state --------------
__device__ __attribute__((aligned(128))) _Float16 g_h1[2*HBUF];
__device__ __attribute__((aligned(128))) _Float16 g_h2[2*HBUF];
__device__ __attribute__((aligned(128))) float g_opart[(size_t)TP*BATCH*128]; // [t][row][slot*4+w]
__device__ __attribute__((aligned(128))) float g_seqT[T_SEQ*BATCH];           // [t][row]
__device__ __attribute__((aligned(128))) unsigned g_bar[8*64];                // per-group, 256B apart

__device__ __forceinline__ rsrc_t mkrsrc(void* p){
  return __builtin_amdgcn_make_buffer_rsrc(p, (short)0, -1, 0x00020000);
}
__device__ __forceinline__ half8 ld_h8(rsrc_t r, int off){
  auto v = __builtin_amdgcn_raw_buffer_load_b128(r, off, 0, SC01);
  return __builtin_bit_cast(half8, v);
}
__device__ __forceinline__ floatx4 ld_f4(rsrc_t r, int off){
  auto v = __builtin_amdgcn_raw_buffer_load_b128(r, off, 0, SC01);
  return __builtin_bit_cast(floatx4, v);
}
__device__ __forceinline__ void st_f(rsrc_t r, int off, float v){
  __builtin_amdgcn_raw_buffer_store_b32(__builtin_bit_cast(unsigned, v), r, off, 0, SC01);
}

__device__ __forceinline__ float sigm(float x){ return 1.0f/(1.0f + __expf(-x)); }
__device__ __forceinline__ float tanh_f(float x){ return 1.0f - 2.0f/(1.0f + __expf(2.0f*x)); }

// Group barrier (32 WGs). Release: vmcnt drain (sc stores acked at LIC) +
// __syncthreads. Device-scope atomics -> placement-independent. Spin guard
// converts any stall into a fast failing run instead of a hang.
__device__ __forceinline__ void xbar(unsigned* cnt, unsigned target, bool& alive, int tid){
  __builtin_amdgcn_s_waitcnt(0);
  __syncthreads();
  if (tid == 0){
    __hip_atomic_fetch_add(cnt, 1u, __ATOMIC_RELAXED, __HIP_MEMORY_SCOPE_AGENT);
    if (alive){
      int guard = 0;
      while (__hip_atomic_load(cnt, __ATOMIC_RELAXED, __HIP_MEMORY_SCOPE_AGENT) < target){
        __builtin_amdgcn_s_sleep(2);
        if (++guard > (1<<22)){ alive = false; break; }
      }
    }
  }
  __syncthreads();
}

// One pipeline phase. Stages this group's 32-row h slices into LDS (swizzled),
// then MFMAs against VGPR-resident weights. DOL1: h1 = lstm(x, h1prev).
// XSEL: 0 = x from seqT, 1 = x from o-partial reduce (+bl).
// DOL2: h2 = lstm(h1r, h2prev) + o-partial store (z2 reuses h1r A-frags).
template<bool DOL1, bool DOL2, int XSEL>
__device__ __forceinline__ void do_phase(
    rsrc_t rh1, rsrc_t rh2, rsrc_t rop, rsrc_t rsq,
    int o_h1r, int o_h2r, int o_h1w, int o_h2w,
    int o_x, float xadd, int t_out,
    _Float16* __restrict__ lA1, _Float16* __restrict__ lA2,
    const half8 (&wf1)[16], const half8 (&wfx)[16], const half8 (&wfh)[16],
    float b1, float b2, float wx, float wl,
    float (&c1v)[2][4], float (&c2v)[2][4],
    int rowbase, int tid, int ln, int quad, int hcb, int sw4)
{
  // ---- stage A slices (32 rows x 512 fp16 each) from LIC into swizzled LDS ----
  {
    const int row = tid >> 3, c8 = tid & 7;
    const int gb1 = o_h1r + (rowbase + row)*H*2;
    const int gb2 = o_h2r + (rowbase + row)*H*2;
    #pragma unroll
    for (int g8 = 0; g8 < 8; ++g8){
      const int gran = c8*8 + g8;
      const int loff = row*512 + ((gran ^ (row&7)) << 3);
      half8 v = ld_h8(rh1, gb1 + gran*16);
      *(half8*)(lA1 + loff) = v;
      if (DOL2){
        half8 u = ld_h8(rh2, gb2 + gran*16);
        *(half8*)(lA2 + loff) = u;
      }
    }
  }

  float xv[2][4];
  if (DOL1){
    #pragma unroll
    for (int mt=0; mt<2; ++mt){
      if (XSEL == 0){
        floatx4 x4 = ld_f4(rsq, o_x + (rowbase + mt*16 + quad*4)*4);
        #pragma unroll
        for (int r=0; r<4; ++r) xv[mt][r] = x4[r] + xadd;
      } else {
        #pragma unroll
        for (int r=0; r<4; ++r){
          const int row = rowbase + mt*16 + quad*4 + r;
          floatx4 v0 = ld_f4(rop, o_x + (row*128 + ln*8)*4);
          floatx4 v1 = ld_f4(rop, o_x + (row*128 + ln*8)*4 + 16);
          float s = v0[0]+v0[1]+v0[2]+v0[3] + v1[0]+v1[1]+v1[2]+v1[3];
          s += __shfl_xor(s, 1, 64);
          s += __shfl_xor(s, 2, 64);
          s += __shfl_xor(s, 4, 64);
          s += __shfl_xor(s, 8, 64);
          xv[mt][r] = s + xadd;
        }
      }
    }
  }
  __syncthreads();   // staging visible WG-wide

  floatx4 z1[2], z2[2];
  floatx4 zf4 = {0.f,0.f,0.f,0.f};
  z1[0]=zf4; z1[1]=zf4; z2[0]=zf4; z2[1]=zf4;

  #pragma unroll
  for (int kk = 0; kk < 16; ++kk){
    const int sw = (((kk*4 + quad) ^ (ln&7)) << 3);
    half8 a10 = *(const half8*)(lA1 + ln*512 + sw);
    half8 a11 = *(const half8*)(lA1 + (16+ln)*512 + sw);
    if (DOL1){
      z1[0] = MFMA(a10, wf1[kk], z1[0]);
      z1[1] = MFMA(a11, wf1[kk], z1[1]);
    }
    if (DOL2){
      z2[0] = MFMA(a10, wfx[kk], z2[0]);
      z2[1] = MFMA(a11, wfx[kk], z2[1]);
      half8 a20 = *(const half8*)(lA2 + ln*512 + sw);
      half8 a21 = *(const half8*)(lA2 + (16+ln)*512 + sw);
      z2[0] = MFMA(a20, wfh[kk], z2[0]);
      z2[1] = MFMA(a21, wfh[kk], z2[1]);
    }
  }

  const bool l4 = (ln < 4);
  const bool evn = ((ln & 1) == 0);
  if (DOL1){
    #pragma unroll
    for (int mt=0; mt<2; ++mt){
      #pragma unroll
      for (int r=0; r<4; ++r){
        const int row = rowbase + mt*16 + quad*4 + r;
        float z = z1[mt][r] + xv[mt][r]*wx + b1;
        float p4  = __shfl_xor(z, 4, 64);
        float p8  = __shfl_xor(z, 8, 64);
        float p12 = __shfl_xor(z, 12, 64);
        float ig = sigm(z), fg = sigm(p4), og = sigm(p8), gg = tanh_f(p12);
        float c = fg*c1v[mt][r] + ig*gg;
        c1v[mt][r] = c;
        float h = og*tanh_f(c);
        unsigned hu = (unsigned)__builtin_bit_cast(unsigned short, (_Float16)h);
        unsigned pn = (unsigned)__shfl_xor((int)hu, 1, 64);
        if (l4 && evn)
          st_f(rh1, o_h1w + (row*H + hcb + ln)*2,
               __builtin_bit_cast(float, hu | (pn<<16)));
      }
    }
  }
  if (DOL2){
    #pragma unroll
    for (int mt=0; mt<2; ++mt){
      #pragma unroll
      for (int r=0; r<4; ++r){
        const int row = rowbase + mt*16 + quad*4 + r;
        float z = z2[mt][r] + b2;
        float p4  = __shfl_xor(z, 4, 64);
        float p8  = __shfl_xor(z, 8, 64);
        float p12 = __shfl_xor(z, 12, 64);
        float ig = sigm(z), fg = sigm(p4), og = sigm(p8), gg = tanh_f(p12);
        float c = fg*c2v[mt][r] + ig*gg;
        c2v[mt][r] = c;
        float h = og*tanh_f(c);
        unsigned hu = (unsigned)__builtin_bit_cast(unsigned short, (_Float16)h);
        unsigned pn = (unsigned)__shfl_xor((int)hu, 1, 64);
        if (l4 && evn)
          st_f(rh2, o_h2w + (row*H + hcb + ln)*2,
               __builtin_bit_cast(float, hu | (pn<<16)));
        float po = l4 ? h*wl : 0.f;
        po += __shfl_xor(po, 1, 64);
        po += __shfl_xor(po, 2, 64);
        if (ln == 0)
          st_f(rop, ((t_out*BATCH + row)*128 + sw4)*4, po);
      }
    }
  }
}

__global__ void reset_kernel(){
  if (threadIdx.x < 8)
    __hip_atomic_store(&g_bar[threadIdx.x*64], 0u, __ATOMIC_RELAXED,
                       __HIP_MEMORY_SCOPE_AGENT);
}

__global__ __launch_bounds__(BLOCK, 1) void sinernn_kernel(
    const float* __restrict__ seq, const float* __restrict__ Wx1,
    const float* __restrict__ bx1, const float* __restrict__ Wh1,
    const float* __restrict__ bh1, const float* __restrict__ Wx2,
    const float* __restrict__ bx2, const float* __restrict__ Wh2,
    const float* __restrict__ bh2, const float* __restrict__ Wl,
    const float* __restrict__ bl,  float* __restrict__ out)
{
  __shared__ __attribute__((aligned(16))) _Float16 lA1[32*512];  // 32 KB
  __shared__ __attribute__((aligned(16))) _Float16 lA2[32*512];  // 32 KB

  const int tid  = threadIdx.x;
  const int wg   = blockIdx.x;
  const int grp  = wg & 7;             // row group 0..7 (XCD-colocated if RR)
  const int slot = wg >> 3;            // 0..31 within group
  const int w    = tid >> 6;
  const int lane = tid & 63;
  const int ln   = lane & 15;
  const int quad = lane >> 4;
  const int rowbase = grp*32;
  const int hcb  = slot*16 + w*4;      // this wave's 4 h-cols
  const int sw4  = slot*4 + w;         // o-partial slot (0..127)
  unsigned* cnt  = &g_bar[grp*64];

  rsrc_t rh1 = mkrsrc((void*)&g_h1[0]);
  rsrc_t rh2 = mkrsrc((void*)&g_h2[0]);
  rsrc_t rop = mkrsrc((void*)&g_opart[0]);
  rsrc_t rsq = mkrsrc((void*)&g_seqT[0]);

  // gate-col: gate = ln>>2, h-col = hcb + (ln&3)
  const int gc = (ln>>2)*H + hcb + (ln&3);

  // ---- prologue: seqT transpose (this WG: 16 t-values x group rows) ----
  for (int i = tid; i < 16*32; i += BLOCK){
    int t = slot*16 + (i>>5), j = i & 31;
    st_f(rsq, (t*BATCH + rowbase + j)*4, seq[(rowbase+j)*T_SEQ + t]);
  }
  // zero h(-1) (buffer 1) for group rows; redundant across slots, benign
  for (int i = tid; i < 32*H/2; i += BLOCK){
    int off = HBYTES + rowbase*H*2 + i*4;
    st_f(rh1, off, 0.f);
    st_f(rh2, off, 0.f);
  }

  // ---- stage all three weight slices into VGPRs (192/lane) ----
  half8 wf1[16], wfx[16], wfh[16];
  #pragma unroll
  for (int kk = 0; kk < 16; ++kk){
    #pragma unroll
    for (int j = 0; j < 8; ++j){
      const int k = kk*32 + quad*8 + j;
      wf1[kk][j] = (_Float16)Wh1[k*G4H + gc];
      wfx[kk][j] = (_Float16)Wx2[k*G4H + gc];
      wfh[kk][j] = (_Float16)Wh2[k*G4H + gc];
    }
  }
  const float b1 = bx1[gc] + bh1[gc];
  const float b2 = bx2[gc] + bh2[gc];
  const float wx = Wx1[gc];
  const float wl = (ln < 4) ? Wl[hcb + (ln&3)] : 0.f;
  const float blv = bl[0];

  float c1v[2][4] = {{0.f,0.f,0.f,0.f},{0.f,0.f,0.f,0.f}};
  float c2v[2][4] = {{0.f,0.f,0.f,0.f},{0.f,0.f,0.f,0.f}};

  unsigned bidx = 0;
  bool alive = true;
  xbar(cnt, (++bidx)*32u, alive, tid);   // prologue visible group-wide

  // ---- main pipelined region: phase p computes h1(p) and h2(p-1) ----
  for (int p = 0; p < T_SEQ; ++p){
    const int b_h1r = ((p+1)&1)*HBYTES;
    const int b_h1w = (p&1)*HBYTES;
    if (p == 0)
      do_phase<true,false,0>(rh1,rh2,rop,rsq, b_h1r,0, b_h1w,0,
                             0, 0.f, -1, lA1, lA2, wf1,wfx,wfh, b1,b2,wx,wl,
                             c1v,c2v, rowbase, tid, ln, quad, hcb, sw4);
    else
      do_phase<true,true,0>(rh1,rh2,rop,rsq, b_h1r,(p&1)*HBYTES,
                            b_h1w,((p+1)&1)*HBYTES,
                            p*BATCH*4, 0.f, p-1, lA1, lA2, wf1,wfx,wfh,
                            b1,b2,wx,wl, c1v,c2v, rowbase, tid, ln, quad, hcb, sw4);
    xbar(cnt, (++bidx)*32u, alive, tid);
  }

  // ---- drain + autoregressive predict ----
  for (int s = T_SEQ-1; s < TP; ++s){
    do_phase<false,true,0>(rh1,rh2,rop,rsq, (s&1)*HBYTES,((s+1)&1)*HBYTES,
                           0,(s&1)*HBYTES,
                           0, 0.f, s, lA1, lA2, wf1,wfx,wfh, b1,b2,wx,wl,
                           c1v,c2v, rowbase, tid, ln, quad, hcb, sw4);
    xbar(cnt, (++bidx)*32u, alive, tid);
    if (s + 1 < TP){
      do_phase<true,false,1>(rh1,rh2,rop,rsq, (s&1)*HBYTES,0,
                             ((s+1)&1)*HBYTES,0,
                             s*BATCH*128*4, blv, -1, lA1, lA2, wf1,wfx,wfh,
                             b1,b2,wx,wl, c1v,c2v, rowbase, tid, ln, quad, hcb, sw4);
      xbar(cnt, (++bidx)*32u, alive, tid);
    }
  }

  // ---- epilogue: out[row][t] = sum_{128} opart[t][row][*] + bl ----
  for (int i = 0; i < 17; ++i){
    const int t = slot + i*32;
    const int rj = tid >> 3;
    const int q8 = tid & 7;
    const int row = rowbase + rj;
    const int base = ((t*BATCH + row)*128 + q8*16)*4;
    float s = 0.f;
    #pragma unroll
    for (int k = 0; k < 4; ++k){
      floatx4 v = ld_f4(rop, base + k*16);
      s += v[0]+v[1]+v[2]+v[3];
    }
    s += __shfl_xor(s, 1, 64);
    s += __shfl_xor(s, 2, 64);
    s += __shfl_xor(s, 4, 64);
    if (q8 == 0) out[row*TP + t] = s + blv;
  }
}

extern "C" void kernel_launch(void* const* d_in, const int* in_sizes, int n_in,
                              void* d_out, int out_size, void* d_ws, size_t ws_size,
                              hipStream_t stream) {
  const float* seq = (const float*)d_in[0];
  // d_in[1] = predict (=32, hardcoded)
  const float* Wx1 = (const float*)d_in[2];
  const float* bx1 = (const float*)d_in[3];
  const float* Wh1 = (const float*)d_in[4];
  const float* bh1 = (const float*)d_in[5];
  const float* Wx2 = (const float*)d_in[6];
  const float* bx2 = (const float*)d_in[7];
  const float* Wh2 = (const float*)d_in[8];
  const float* bh2 = (const float*)d_in[9];
  const float* Wl  = (const float*)d_in[10];
  const float* bl  = (const float*)d_in[11];
  float* out = (float*)d_out;

  reset_kernel<<<1, 64, 0, stream>>>();

  sinernn_kernel<<<dim3(GRID), dim3(BLOCK), 0, stream>>>(
      seq, Wx1, bx1, Wh1, bh1, Wx2, bx2, Wh2, bh2, Wl, bl, out);
}